// Round 3
// baseline (315.956 us; speedup 1.0000x reference)
//
#include <hip/hip_runtime.h>

#define BATCH 262144
#define EMB 300
#define NBLK 4096
#define WPB 4          // waves per block
#define PPW 16         // pairs per wave, fully unrolled: NBLK*WPB*PPW == BATCH

__global__ __launch_bounds__(256) void glove_main(
    const int*   __restrict__ center,
    const int*   __restrict__ outside,
    const float* __restrict__ coocs,
    const float* __restrict__ weighting,
    const float* __restrict__ cemb,
    const float* __restrict__ oemb,
    const float* __restrict__ cbias,
    const float* __restrict__ obias,
    float*       __restrict__ block_sums)
{
    const int lane = threadIdx.x & 63;
    const int warp = threadIdx.x >> 6;
    const int base = (blockIdx.x * WPB + warp) * PPW;

    int ci[PPW], oi[PPW];
    #pragma unroll
    for (int j = 0; j < PPW; ++j) {
        ci[j] = center[base + j];
        oi[j] = outside[base + j];
    }

    // 32 full + 32 tail dwordx4 row loads in one straight-line region:
    // compiler pipelines with staggered vmcnt, consuming into 16 accumulators.
    float acc[PPW];
    #pragma unroll
    for (int j = 0; j < PPW; ++j) {
        const float4* __restrict__ A = (const float4*)(cemb + (long)ci[j] * EMB);
        const float4* __restrict__ B = (const float4*)(oemb + (long)oi[j] * EMB);
        float4 a = A[lane];
        float4 b = B[lane];
        float s = a.x * b.x + a.y * b.y + a.z * b.z + a.w * b.w;
        if (lane < 11) {                 // 75 float4/row: lanes 0..10 cover [64,75)
            float4 a2 = A[lane + 64];
            float4 b2 = B[lane + 64];
            s += a2.x * b2.x + a2.y * b2.y + a2.z * b2.z + a2.w * b2.w;
        }
        acc[j] = s;
    }

    // small per-pair scalars: issue now, latency hides under the shuffle chain
    float cb[PPW], ob2[PPW], cc[PPW], wt[PPW];
    #pragma unroll
    for (int j = 0; j < PPW; ++j) {
        cc[j]  = coocs[base + j];
        wt[j]  = weighting[base + j];
        cb[j]  = cbias[ci[j]];
        ob2[j] = obias[oi[j]];
    }

    // 16 interleaved reduction chains: 6 lgkm wait points for all 16 pairs
    #pragma unroll
    for (int off = 32; off > 0; off >>= 1) {
        #pragma unroll
        for (int j = 0; j < PPW; ++j)
            acc[j] += __shfl_down(acc[j], off, 64);
    }

    float local = 0.0f;
    if (lane == 0) {
        #pragma unroll
        for (int j = 0; j < PPW; ++j) {
            const float e = acc[j] + cb[j] + ob2[j] - cc[j];
            local += wt[j] * e * e;
        }
    }

    __shared__ float smem[WPB];
    if (lane == 0) smem[warp] = local;
    __syncthreads();
    if (threadIdx.x == 0)
        block_sums[blockIdx.x] = smem[0] + smem[1] + smem[2] + smem[3];
}

__global__ __launch_bounds__(1024) void glove_reduce(
    const float* __restrict__ part, float* __restrict__ out)
{
    const int t = threadIdx.x;
    float4 v = ((const float4*)part)[t];          // 1024 x 4 = 4096 partials
    float s = v.x + v.y + v.z + v.w;
    #pragma unroll
    for (int off = 32; off > 0; off >>= 1)
        s += __shfl_down(s, off, 64);
    __shared__ float sm[16];
    if ((t & 63) == 0) sm[t >> 6] = s;
    __syncthreads();
    if (t < 16) {
        float x = sm[t];
        #pragma unroll
        for (int off = 8; off > 0; off >>= 1)
            x += __shfl_down(x, off, 16);
        if (t == 0) out[0] = x;
    }
}

extern "C" void kernel_launch(void* const* d_in, const int* in_sizes, int n_in,
                              void* d_out, int out_size, void* d_ws, size_t ws_size,
                              hipStream_t stream) {
    const int*   center    = (const int*)  d_in[0];
    const int*   outside   = (const int*)  d_in[1];
    const float* coocs     = (const float*)d_in[2];
    const float* weighting = (const float*)d_in[3];
    const float* cemb      = (const float*)d_in[4];
    const float* oemb      = (const float*)d_in[5];
    const float* cbias     = (const float*)d_in[6];
    const float* obias     = (const float*)d_in[7];
    float* out        = (float*)d_out;
    float* block_sums = (float*)d_ws;   // NBLK floats = 16 KB, fully overwritten

    glove_main<<<NBLK, 256, 0, stream>>>(
        center, outside, coocs, weighting, cemb, oemb, cbias, obias, block_sums);
    glove_reduce<<<1, 1024, 0, stream>>>(block_sums, out);
}

// Round 5
// 304.505 us; speedup vs baseline: 1.0376x; 1.0376x over previous
//
#include <hip/hip_runtime.h>

#define BATCH 262144
#define EMB 300
#define NBLK 4096
#define WPB 4
// 16 lanes per pair, 4 pair-groups per wave, 4 steps => 16 pairs/wave
// NBLK * WPB * 16 == BATCH

__global__ __launch_bounds__(256) void glove_main(
    const int*   __restrict__ center,
    const int*   __restrict__ outside,
    const float* __restrict__ coocs,
    const float* __restrict__ weighting,
    const float* __restrict__ cemb,
    const float* __restrict__ oemb,
    const float* __restrict__ cbias,
    const float* __restrict__ obias,
    float*       __restrict__ block_sums)
{
    const int tid  = threadIdx.x;
    const int warp = tid >> 6;
    const int lane = tid & 63;
    const int l    = lane & 15;   // lane within 16-lane pair-group
    const int g    = lane >> 4;   // pair-group 0..3
    const int base = (blockIdx.x * WPB + warp) * 16 + g;

    int ci[4], oi[4];
    #pragma unroll
    for (int it = 0; it < 4; ++it) {
        ci[it] = center[base + it * 4];
        oi[it] = outside[base + it * 4];
    }

    // double-buffered stage registers (no structs, no helpers: ICE-defensive)
    float4 sa[2][5], sb[2][5];
    float  scb[2], sob[2], scc[2], swt[2];

    // ---- prologue: load stages 0 and 1 ----
    #pragma unroll
    for (int s = 0; s < 2; ++s) {
        const float4* __restrict__ A = (const float4*)(cemb + (long)ci[s] * EMB);
        const float4* __restrict__ B = (const float4*)(oemb + (long)oi[s] * EMB);
        #pragma unroll
        for (int i = 0; i < 4; ++i) {
            sa[s][i] = A[i * 16 + l];
            sb[s][i] = B[i * 16 + l];
        }
        sa[s][4].x = 0.f; sa[s][4].y = 0.f; sa[s][4].z = 0.f; sa[s][4].w = 0.f;
        sb[s][4] = sa[s][4];
        if (l < 11) {               // 75 float4/row: lanes 0..10 cover [64,75)
            sa[s][4] = A[64 + l];
            sb[s][4] = B[64 + l];
        }
        scb[s] = cbias[ci[s]];
        sob[s] = obias[oi[s]];
        scc[s] = coocs[base + s * 4];
        swt[s] = weighting[base + s * 4];
    }

    float local = 0.0f;

    // ---- pipelined main: compute stage it from buf, refill buf with it+2 ----
    #pragma unroll
    for (int it = 0; it < 4; ++it) {
        const int buf = it & 1;

        float s = 0.f;
        #pragma unroll
        for (int i = 0; i < 5; ++i) {
            s += sa[buf][i].x * sb[buf][i].x + sa[buf][i].y * sb[buf][i].y
               + sa[buf][i].z * sb[buf][i].z + sa[buf][i].w * sb[buf][i].w;
        }
        const float cbv = scb[buf], obv = sob[buf], ccv = scc[buf], wtv = swt[buf];

        // refill this buffer with stage it+2 BEFORE the butterfly waits,
        // so the next loads fly under the DS chain
        if (it + 2 < 4) {
            const int n = it + 2;
            const float4* __restrict__ A = (const float4*)(cemb + (long)ci[n] * EMB);
            const float4* __restrict__ B = (const float4*)(oemb + (long)oi[n] * EMB);
            #pragma unroll
            for (int i = 0; i < 4; ++i) {
                sa[buf][i] = A[i * 16 + l];
                sb[buf][i] = B[i * 16 + l];
            }
            if (l < 11) {
                sa[buf][4] = A[64 + l];
                sb[buf][4] = B[64 + l];
            } else {
                sa[buf][4].x = 0.f; sa[buf][4].y = 0.f; sa[buf][4].z = 0.f; sa[buf][4].w = 0.f;
                sb[buf][4] = sa[buf][4];
            }
            scb[buf] = cbias[ci[n]];
            sob[buf] = obias[oi[n]];
            scc[buf] = coocs[base + n * 4];
            swt[buf] = weighting[base + n * 4];
        }

        // 4-step butterfly within the 16-lane group (masks < 16 stay in-group)
        s += __shfl_xor(s, 1);
        s += __shfl_xor(s, 2);
        s += __shfl_xor(s, 4);
        s += __shfl_xor(s, 8);

        if (l == 0) {
            const float e = s + cbv + obv - ccv;
            local += wtv * e * e;
        }
    }

    // gather the 4 group-leaders (lanes 0,16,32,48) to lane 0
    local += __shfl_down(local, 32, 64);
    local += __shfl_down(local, 16, 64);

    __shared__ float smem[WPB];
    if (lane == 0) smem[warp] = local;
    __syncthreads();
    if (tid == 0)
        block_sums[blockIdx.x] = smem[0] + smem[1] + smem[2] + smem[3];
}

__global__ __launch_bounds__(1024) void glove_reduce(
    const float* __restrict__ part, float* __restrict__ out)
{
    const int t = threadIdx.x;
    float4 v = ((const float4*)part)[t];          // 1024 x 4 = 4096 partials
    float s = v.x + v.y + v.z + v.w;
    #pragma unroll
    for (int off = 32; off > 0; off >>= 1)
        s += __shfl_down(s, off, 64);
    __shared__ float sm[16];
    if ((t & 63) == 0) sm[t >> 6] = s;
    __syncthreads();
    if (t < 16) {
        float x = sm[t];
        #pragma unroll
        for (int off = 8; off > 0; off >>= 1)
            x += __shfl_down(x, off, 16);
        if (t == 0) out[0] = x;
    }
}

extern "C" void kernel_launch(void* const* d_in, const int* in_sizes, int n_in,
                              void* d_out, int out_size, void* d_ws, size_t ws_size,
                              hipStream_t stream) {
    const int*   center    = (const int*)  d_in[0];
    const int*   outside   = (const int*)  d_in[1];
    const float* coocs     = (const float*)d_in[2];
    const float* weighting = (const float*)d_in[3];
    const float* cemb      = (const float*)d_in[4];
    const float* oemb      = (const float*)d_in[5];
    const float* cbias     = (const float*)d_in[6];
    const float* obias     = (const float*)d_in[7];
    float* out        = (float*)d_out;
    float* block_sums = (float*)d_ws;   // NBLK floats = 16 KB, fully overwritten

    glove_main<<<NBLK, 256, 0, stream>>>(
        center, outside, coocs, weighting, cemb, oemb, cbias, obias, block_sums);
    glove_reduce<<<1, 1024, 0, stream>>>(block_sums, out);
}